// Round 1
// baseline (1086.762 us; speedup 1.0000x reference)
//
#include <hip/hip_runtime.h>
#include <hip/hip_bf16.h>

// Problem constants
#define NA   50000      // atoms
#define MN   12         // neighbors
#define FD   128        // atom feature len
#define KD   64         // nbr feature len
#define NMR  600000     // NA*MN edge rows
#define KIN  320        // 2F+K
#define BN_EPS 1e-5f

#define NBLK2 1536      // k2 grid (persistent-ish)
#define NBLK3 782       // ceil(NA/64)

__device__ __forceinline__ float softplusf(float x) {
    return fmaxf(x, 0.f) + log1pf(__expf(-fabsf(x)));
}
__device__ __forceinline__ float sigmoidf_(float x) {
    return 1.f / (1.f + __expf(-x));
}

// ---------------------------------------------------------------------------
// K1: P12[n][0:256] = atom@W1^T, P12[n][256:512] = atom@W2^T   (bias skipped:
// it cancels exactly through BN1's mean subtraction)
// Block: 64 rows x 256 cols, 256 threads, each 4 rows x 16 cols, TK=32.
// ---------------------------------------------------------------------------
__global__ __launch_bounds__(256) void k1_p12(const float* __restrict__ atom,
                                              const float* __restrict__ W,
                                              float* __restrict__ P12) {
    __shared__ float sA[32 * 68];    // [k][row], stride 68 (16B-aligned rows, 2-4 way wr conflicts only)
    __shared__ float sW[32 * 260];   // [k][col], stride 260
    const int t  = threadIdx.x;
    const int tx = t & 15, ty = t >> 4;
    const int r0  = blockIdx.x * 64;
    const int yb  = blockIdx.y;          // 0 -> W cols 0..127 (P1), 1 -> 128..255 (P2)
    const int kwb = yb * 128;

    float acc[4][16];
#pragma unroll
    for (int r = 0; r < 4; r++)
#pragma unroll
        for (int c = 0; c < 16; c++) acc[r][c] = 0.f;

    const int arow = t >> 3;           // 0..31
    const int akk  = (t & 7) * 4;      // 0..28
    const int wf   = t & 31;
    const int wkk  = (t >> 5) * 4;     // 0..28

    for (int k0 = 0; k0 < 128; k0 += 32) {
        // stage A (transposed [k][row])
#pragma unroll
        for (int h = 0; h < 2; h++) {
            int row  = r0 + arow + h * 32;
            int rowc = row < NA ? row : NA - 1;
            float4 v = *(const float4*)&atom[(size_t)rowc * FD + k0 + akk];
            sA[(akk + 0) * 68 + arow + h * 32] = v.x;
            sA[(akk + 1) * 68 + arow + h * 32] = v.y;
            sA[(akk + 2) * 68 + arow + h * 32] = v.z;
            sA[(akk + 3) * 68 + arow + h * 32] = v.w;
        }
        // stage W block (transposed [k][f])
#pragma unroll
        for (int i = 0; i < 8; i++) {
            int f = wf + i * 32;
            float4 v = *(const float4*)&W[(size_t)f * KIN + kwb + k0 + wkk];
            sW[(wkk + 0) * 260 + f] = v.x;
            sW[(wkk + 1) * 260 + f] = v.y;
            sW[(wkk + 2) * 260 + f] = v.z;
            sW[(wkk + 3) * 260 + f] = v.w;
        }
        __syncthreads();
#pragma unroll 8
        for (int k = 0; k < 32; k++) {
            float4 a = *(const float4*)&sA[k * 68 + ty * 4];
            float a4[4] = {a.x, a.y, a.z, a.w};
#pragma unroll
            for (int j = 0; j < 4; j++) {
                float4 w = *(const float4*)&sW[k * 260 + j * 64 + tx * 4];
#pragma unroll
                for (int r = 0; r < 4; r++) {
                    acc[r][j*4+0] = fmaf(a4[r], w.x, acc[r][j*4+0]);
                    acc[r][j*4+1] = fmaf(a4[r], w.y, acc[r][j*4+1]);
                    acc[r][j*4+2] = fmaf(a4[r], w.z, acc[r][j*4+2]);
                    acc[r][j*4+3] = fmaf(a4[r], w.w, acc[r][j*4+3]);
                }
            }
        }
        __syncthreads();
    }
#pragma unroll
    for (int rr = 0; rr < 4; rr++) {
        int row = r0 + ty * 4 + rr;
        if (row < NA) {
            float* dst = &P12[(size_t)row * 512 + yb * 256];
#pragma unroll
            for (int j = 0; j < 4; j++) {
                float4 v = make_float4(acc[rr][j*4+0], acc[rr][j*4+1],
                                       acc[rr][j*4+2], acc[rr][j*4+3]);
                *(float4*)&dst[j * 64 + tx * 4] = v;
            }
        }
    }
}

// ---------------------------------------------------------------------------
// K2: gated[g][c] = P1[n][c] + mask*(P2[idx[g]][c] + (nbr_fea[g]@W3^T)[c])
// stored bf16; per-column sum/sumsq partials (f32, from pre-rounding values).
// Block: 64 edge-rows x 256 cols, persistent over tiles.
// ---------------------------------------------------------------------------
struct BF4 { __hip_bfloat162 a, b; };

__global__ __launch_bounds__(256) void k2_gated(const float* __restrict__ nbr,
                                                const int* __restrict__ nidx,
                                                const float* __restrict__ W,
                                                const float* __restrict__ P12,
                                                __hip_bfloat16* __restrict__ gated,
                                                float* __restrict__ partial1) {
    __shared__ float smem[32 * 68 + 32 * 260];
    float* sA = smem;
    float* sW = smem + 32 * 68;
    const int t  = threadIdx.x;
    const int tx = t & 15, ty = t >> 4;
    const int arow = t >> 3;
    const int akk  = (t & 7) * 4;
    const int wf   = t & 31;
    const int wkk  = (t >> 5) * 4;

    float ssum[16], ssq[16];
#pragma unroll
    for (int i = 0; i < 16; i++) { ssum[i] = 0.f; ssq[i] = 0.f; }

    for (int tile = blockIdx.x; tile < NMR / 64; tile += NBLK2) {
        const int g0 = tile * 64;
        float acc[4][16];
#pragma unroll
        for (int r = 0; r < 4; r++)
#pragma unroll
            for (int c = 0; c < 16; c++) acc[r][c] = 0.f;

        for (int k0 = 0; k0 < 64; k0 += 32) {
#pragma unroll
            for (int h = 0; h < 2; h++) {
                int row = g0 + arow + h * 32;
                float4 v = *(const float4*)&nbr[(size_t)row * KD + k0 + akk];
                sA[(akk + 0) * 68 + arow + h * 32] = v.x;
                sA[(akk + 1) * 68 + arow + h * 32] = v.y;
                sA[(akk + 2) * 68 + arow + h * 32] = v.z;
                sA[(akk + 3) * 68 + arow + h * 32] = v.w;
            }
#pragma unroll
            for (int i = 0; i < 8; i++) {
                int f = wf + i * 32;
                float4 v = *(const float4*)&W[(size_t)f * KIN + 256 + k0 + wkk];
                sW[(wkk + 0) * 260 + f] = v.x;
                sW[(wkk + 1) * 260 + f] = v.y;
                sW[(wkk + 2) * 260 + f] = v.z;
                sW[(wkk + 3) * 260 + f] = v.w;
            }
            __syncthreads();
#pragma unroll 8
            for (int k = 0; k < 32; k++) {
                float4 a = *(const float4*)&sA[k * 68 + ty * 4];
                float a4[4] = {a.x, a.y, a.z, a.w};
#pragma unroll
                for (int j = 0; j < 4; j++) {
                    float4 w = *(const float4*)&sW[k * 260 + j * 64 + tx * 4];
#pragma unroll
                    for (int r = 0; r < 4; r++) {
                        acc[r][j*4+0] = fmaf(a4[r], w.x, acc[r][j*4+0]);
                        acc[r][j*4+1] = fmaf(a4[r], w.y, acc[r][j*4+1]);
                        acc[r][j*4+2] = fmaf(a4[r], w.z, acc[r][j*4+2]);
                        acc[r][j*4+3] = fmaf(a4[r], w.w, acc[r][j*4+3]);
                    }
                }
            }
            __syncthreads();
        }
        // epilogue: gather P1/P2, mask, store bf16, accumulate stats
#pragma unroll
        for (int rr = 0; rr < 4; rr++) {
            int g  = g0 + ty * 4 + rr;
            int n  = g / MN;
            int iv = nidx[g];
            float mk = (iv != 0) ? 1.f : 0.f;
            const float* p1 = &P12[(size_t)n * 512];
            const float* p2 = &P12[(size_t)iv * 512 + 256];
            __hip_bfloat16* gd = &gated[(size_t)g * 256];
#pragma unroll
            for (int j = 0; j < 4; j++) {
                int c = j * 64 + tx * 4;
                float4 a = *(const float4*)&p1[c];
                float4 b = *(const float4*)&p2[c];
                float v0 = a.x + mk * (b.x + acc[rr][j*4+0]);
                float v1 = a.y + mk * (b.y + acc[rr][j*4+1]);
                float v2 = a.z + mk * (b.z + acc[rr][j*4+2]);
                float v3 = a.w + mk * (b.w + acc[rr][j*4+3]);
                BF4 pk;
                pk.a.x = __float2bfloat16(v0); pk.a.y = __float2bfloat16(v1);
                pk.b.x = __float2bfloat16(v2); pk.b.y = __float2bfloat16(v3);
                *(BF4*)&gd[c] = pk;
                ssum[j*4+0] += v0; ssq[j*4+0] += v0 * v0;
                ssum[j*4+1] += v1; ssq[j*4+1] += v1 * v1;
                ssum[j*4+2] += v2; ssq[j*4+2] += v2 * v2;
                ssum[j*4+3] += v3; ssq[j*4+3] += v3 * v3;
            }
        }
    }
    // block-level column reduction -> partial1[block][512]
    __syncthreads();
    float* red = smem;   // 16*256 floats fits
#pragma unroll
    for (int j = 0; j < 4; j++)
#pragma unroll
        for (int q = 0; q < 4; q++)
            red[ty * 256 + j * 64 + tx * 4 + q] = ssum[j * 4 + q];
    __syncthreads();
    {
        float s = 0.f;
#pragma unroll
        for (int q = 0; q < 16; q++) s += red[q * 256 + t];
        partial1[(size_t)blockIdx.x * 512 + t] = s;
    }
    __syncthreads();
#pragma unroll
    for (int j = 0; j < 4; j++)
#pragma unroll
        for (int q = 0; q < 4; q++)
            red[ty * 256 + j * 64 + tx * 4 + q] = ssq[j * 4 + q];
    __syncthreads();
    {
        float s = 0.f;
#pragma unroll
        for (int q = 0; q < 16; q++) s += red[q * 256 + t];
        partial1[(size_t)blockIdx.x * 512 + 256 + t] = s;
    }
}

// ---------------------------------------------------------------------------
// K2b: finalize BN1 -> bn1[c]=scale, bn1[256+c]=shift (one block per column)
// ---------------------------------------------------------------------------
__global__ __launch_bounds__(64) void k2b_bn1(const float* __restrict__ partial1,
                                              const float* __restrict__ gamma1,
                                              const float* __restrict__ beta1,
                                              float* __restrict__ bn1) {
    const int c = blockIdx.x;    // 0..255
    const int t = threadIdx.x;   // 64
    double s = 0.0, q = 0.0;
    for (int b = t; b < NBLK2; b += 64) {
        s += (double)partial1[(size_t)b * 512 + c];
        q += (double)partial1[(size_t)b * 512 + 256 + c];
    }
#pragma unroll
    for (int off = 32; off > 0; off >>= 1) {
        s += __shfl_down(s, off);
        q += __shfl_down(q, off);
    }
    if (t == 0) {
        double mean = s / (double)NMR;
        double var  = q / (double)NMR - mean * mean;
        float scale = gamma1[c] * rsqrtf((float)var + BN_EPS);
        bn1[c]       = scale;
        bn1[256 + c] = fmaf(-(float)mean, scale, beta1[c]);
    }
}

// ---------------------------------------------------------------------------
// K3: BN1 + sigmoid*softplus*mask, sum over M -> nbr_sumed (f32);
// per-column partials for BN2.
// ---------------------------------------------------------------------------
__global__ __launch_bounds__(256) void k3_sum(const __hip_bfloat16* __restrict__ gated,
                                              const int* __restrict__ nidx,
                                              const float* __restrict__ bn1,
                                              float* __restrict__ nsum,
                                              float* __restrict__ partial2) {
    const int b = blockIdx.x;
    const int t = threadIdx.x;
    const int c    = t & 127;
    const int half = t >> 7;
    const int n0   = b * 64;
    const int nend = min(n0 + 64, NA);
    const float sc_f = bn1[c],       sh_f = bn1[256 + c];
    const float sc_c = bn1[128 + c], sh_c = bn1[384 + c];
    float ls = 0.f, lq = 0.f;
    for (int n = n0 + half; n < nend; n += 2) {
        float s = 0.f;
        const size_t gbase = (size_t)n * MN;
#pragma unroll
        for (int m = 0; m < MN; m++) {
            size_t g = gbase + m;
            float mk = (nidx[g] != 0) ? 1.f : 0.f;
            float xf = __bfloat162float(gated[g * 256 + c]);
            float xc = __bfloat162float(gated[g * 256 + 128 + c]);
            xf = fmaf(xf, sc_f, sh_f);
            xc = fmaf(xc, sc_c, sh_c);
            s += sigmoidf_(xf) * softplusf(xc) * mk;
        }
        nsum[(size_t)n * 128 + c] = s;
        ls += s; lq += s * s;
    }
    __shared__ float red[512];
    red[t] = ls;
    red[256 + t] = lq;
    __syncthreads();
    if (t < 128) {
        partial2[(size_t)b * 256 + t]       = red[t] + red[t + 128];
        partial2[(size_t)b * 256 + 128 + t] = red[256 + t] + red[256 + t + 128];
    }
}

// ---------------------------------------------------------------------------
// K3b: finalize BN2 -> bn2[c]=scale, bn2[128+c]=shift
// ---------------------------------------------------------------------------
__global__ __launch_bounds__(64) void k3b_bn2(const float* __restrict__ partial2,
                                              const float* __restrict__ gamma2,
                                              const float* __restrict__ beta2,
                                              float* __restrict__ bn2) {
    const int c = blockIdx.x;    // 0..127
    const int t = threadIdx.x;
    double s = 0.0, q = 0.0;
    for (int b = t; b < NBLK3; b += 64) {
        s += (double)partial2[(size_t)b * 256 + c];
        q += (double)partial2[(size_t)b * 256 + 128 + c];
    }
#pragma unroll
    for (int off = 32; off > 0; off >>= 1) {
        s += __shfl_down(s, off);
        q += __shfl_down(q, off);
    }
    if (t == 0) {
        double mean = s / (double)NA;
        double var  = q / (double)NA - mean * mean;
        float scale = gamma2[c] * rsqrtf((float)var + BN_EPS);
        bn2[c]       = scale;
        bn2[128 + c] = fmaf(-(float)mean, scale, beta2[c]);
    }
}

// ---------------------------------------------------------------------------
// K4: out = softplus(atom_in + nbr_sumed*scale2 + shift2)
// ---------------------------------------------------------------------------
__global__ __launch_bounds__(256) void k4_out(const float* __restrict__ atom,
                                              const float* __restrict__ nsum,
                                              const float* __restrict__ bn2,
                                              float* __restrict__ out) {
    const int i  = blockIdx.x * 256 + threadIdx.x;   // float4 index, 1.6M exact
    const int c0 = (i & 31) * 4;
    float4 a = ((const float4*)atom)[i];
    float4 s = ((const float4*)nsum)[i];
    float4 r;
    r.x = softplusf(a.x + fmaf(s.x, bn2[c0 + 0], bn2[128 + c0 + 0]));
    r.y = softplusf(a.y + fmaf(s.y, bn2[c0 + 1], bn2[128 + c0 + 1]));
    r.z = softplusf(a.z + fmaf(s.z, bn2[c0 + 2], bn2[128 + c0 + 2]));
    r.w = softplusf(a.w + fmaf(s.w, bn2[c0 + 3], bn2[128 + c0 + 3]));
    ((float4*)out)[i] = r;
}

// ---------------------------------------------------------------------------
extern "C" void kernel_launch(void* const* d_in, const int* in_sizes, int n_in,
                              void* d_out, int out_size, void* d_ws, size_t ws_size,
                              hipStream_t stream) {
    const float* atom   = (const float*)d_in[0];
    const float* nbr    = (const float*)d_in[1];
    const int*   nidx   = (const int*)d_in[2];
    const float* W      = (const float*)d_in[3];
    // d_in[4] = b : unused — cancels exactly through BN1 mean subtraction
    const float* gamma1 = (const float*)d_in[5];
    const float* beta1  = (const float*)d_in[6];
    const float* gamma2 = (const float*)d_in[7];
    const float* beta2  = (const float*)d_in[8];
    float* out = (float*)d_out;

    // ws layout (f32 units); total ~ 440 MB
    float* ws       = (float*)d_ws;
    float* P12      = ws;                                  // NA*512
    float* nsum     = P12      + (size_t)NA * 512;         // NA*128
    float* partial1 = nsum     + (size_t)NA * 128;         // NBLK2*512
    float* partial2 = partial1 + (size_t)NBLK2 * 512;      // NBLK3*256
    float* bn1      = partial2 + (size_t)NBLK3 * 256;      // 512
    float* bn2      = bn1 + 512;                           // 256
    __hip_bfloat16* gated = (__hip_bfloat16*)(bn2 + 256);  // NMR*256 bf16

    k1_p12 <<<dim3(782, 2), 256, 0, stream>>>(atom, W, P12);
    k2_gated<<<NBLK2,       256, 0, stream>>>(nbr, nidx, W, P12, gated, partial1);
    k2b_bn1<<<256,           64, 0, stream>>>(partial1, gamma1, beta1, bn1);
    k3_sum <<<NBLK3,        256, 0, stream>>>(gated, nidx, bn1, nsum, partial2);
    k3b_bn2<<<128,           64, 0, stream>>>(partial2, gamma2, beta2, bn2);
    k4_out <<<6250,         256, 0, stream>>>(atom, nsum, bn2, out);
}

// Round 2
// 767.617 us; speedup vs baseline: 1.4158x; 1.4158x over previous
//
#include <hip/hip_runtime.h>

typedef unsigned int u32;
typedef unsigned short u16;
typedef __attribute__((ext_vector_type(8))) short short8;
typedef __attribute__((ext_vector_type(16))) float f32x16;

// Problem constants
#define NA   50000      // atoms
#define MN   12         // neighbors
#define FD   128        // atom feature len
#define KD   64         // nbr feature len
#define NMR  600000     // NA*MN edge rows
#define KIN  320        // 2F+K
#define NT2  9375       // NMR/64 tiles
#define NBLK2 512       // k2 persistent blocks (2 blocks/CU x 256 CU)
#define NBLK3 3125      // k3 blocks (16 atoms each)
#define BN_EPS 1e-5f

__device__ __forceinline__ float softplusf(float x) {
    return fmaxf(x, 0.f) + log1pf(__expf(-fabsf(x)));
}
__device__ __forceinline__ float sigmoidf_(float x) {
    return 1.f / (1.f + __expf(-x));
}

// ---- manual bf16 (RNE) helpers: no dependence on hip_bf16 API ----
__device__ __forceinline__ u32 f2bf_bits(float f) {   // rounded bits in top 16
    u32 u = __float_as_uint(f);
    return u + 0x7fffu + ((u >> 16) & 1u);
}
__device__ __forceinline__ u32 pack2(float lo, float hi) {
    return (f2bf_bits(lo) >> 16) | (f2bf_bits(hi) & 0xffff0000u);
}
__device__ __forceinline__ float bflo(u32 u) { return __uint_as_float(u << 16); }
__device__ __forceinline__ float bfhi(u32 u) { return __uint_as_float(u & 0xffff0000u); }
__device__ __forceinline__ short8 pack8(float4 x, float4 y) {
    union { short8 s; uint4 u; } cv;
    cv.u = make_uint4(pack2(x.x, x.y), pack2(x.z, x.w),
                      pack2(y.x, y.y), pack2(y.z, y.w));
    return cv.s;
}
__device__ __forceinline__ void unp8(uint4 u, float* f) {
    f[0] = bflo(u.x); f[1] = bfhi(u.x); f[2] = bflo(u.y); f[3] = bfhi(u.y);
    f[4] = bflo(u.z); f[5] = bfhi(u.z); f[6] = bflo(u.w); f[7] = bfhi(u.w);
}

// ---------------------------------------------------------------------------
// K1: P12[n][0:256] = atom@W1^T, P12[n][256:512] = atom@W2^T  (bf16 output).
// Bias skipped: cancels exactly through BN1 mean subtraction.
// Block: 64 rows x 256 cols, 256 threads, f32 VALU GEMM (only 1.6 G FMA).
// ---------------------------------------------------------------------------
__global__ __launch_bounds__(256) void k1_p12(const float* __restrict__ atom,
                                              const float* __restrict__ W,
                                              u16* __restrict__ P12) {
    __shared__ float sA[32 * 68];
    __shared__ float sW[32 * 260];
    const int t  = threadIdx.x;
    const int tx = t & 15, ty = t >> 4;
    const int r0  = blockIdx.x * 64;
    const int yb  = blockIdx.y;          // 0 -> P1 (W cols 0..127), 1 -> P2 (128..255)
    const int kwb = yb * 128;

    float acc[4][16];
#pragma unroll
    for (int r = 0; r < 4; r++)
#pragma unroll
        for (int c = 0; c < 16; c++) acc[r][c] = 0.f;

    const int arow = t >> 3;
    const int akk  = (t & 7) * 4;
    const int wf   = t & 31;
    const int wkk  = (t >> 5) * 4;

    for (int k0 = 0; k0 < 128; k0 += 32) {
#pragma unroll
        for (int h = 0; h < 2; h++) {
            int row  = r0 + arow + h * 32;
            int rowc = row < NA ? row : NA - 1;
            float4 v = *(const float4*)&atom[(size_t)rowc * FD + k0 + akk];
            sA[(akk + 0) * 68 + arow + h * 32] = v.x;
            sA[(akk + 1) * 68 + arow + h * 32] = v.y;
            sA[(akk + 2) * 68 + arow + h * 32] = v.z;
            sA[(akk + 3) * 68 + arow + h * 32] = v.w;
        }
#pragma unroll
        for (int i = 0; i < 8; i++) {
            int f = wf + i * 32;
            float4 v = *(const float4*)&W[(size_t)f * KIN + kwb + k0 + wkk];
            sW[(wkk + 0) * 260 + f] = v.x;
            sW[(wkk + 1) * 260 + f] = v.y;
            sW[(wkk + 2) * 260 + f] = v.z;
            sW[(wkk + 3) * 260 + f] = v.w;
        }
        __syncthreads();
#pragma unroll 8
        for (int k = 0; k < 32; k++) {
            float4 a = *(const float4*)&sA[k * 68 + ty * 4];
            float a4[4] = {a.x, a.y, a.z, a.w};
#pragma unroll
            for (int j = 0; j < 4; j++) {
                float4 w = *(const float4*)&sW[k * 260 + j * 64 + tx * 4];
#pragma unroll
                for (int r = 0; r < 4; r++) {
                    acc[r][j*4+0] = fmaf(a4[r], w.x, acc[r][j*4+0]);
                    acc[r][j*4+1] = fmaf(a4[r], w.y, acc[r][j*4+1]);
                    acc[r][j*4+2] = fmaf(a4[r], w.z, acc[r][j*4+2]);
                    acc[r][j*4+3] = fmaf(a4[r], w.w, acc[r][j*4+3]);
                }
            }
        }
        __syncthreads();
    }
#pragma unroll
    for (int rr = 0; rr < 4; rr++) {
        int row = r0 + ty * 4 + rr;
        if (row < NA) {
            u16* dst = &P12[(size_t)row * 512 + yb * 256];
#pragma unroll
            for (int j = 0; j < 4; j++) {
                u32 lo = pack2(acc[rr][j*4+0], acc[rr][j*4+1]);
                u32 hi = pack2(acc[rr][j*4+2], acc[rr][j*4+3]);
                *(uint2*)&dst[j * 64 + tx * 4] = make_uint2(lo, hi);
            }
        }
    }
}

// ---------------------------------------------------------------------------
// K2 (MFMA): Q = nbr @ W3^T via mfma_f32_32x32x16_bf16, B stationary in VGPRs
// (64 regs/lane, zero LDS reads in K-loop). C staged through LDS into a
// linear layout; epilogue fuses P1 + mask*(P2 + Q), bf16 store, BN1 partials.
// Block: 4 waves; tile 64 rows x 256 cols; wave w: rows 32*(w&1), cols 128*(w>>1).
// ---------------------------------------------------------------------------
__global__ __launch_bounds__(256, 2) void k2_gated(const float* __restrict__ nbr,
                                                   const int* __restrict__ nidx,
                                                   const float* __restrict__ W,
                                                   const u16* __restrict__ P12,
                                                   u16* __restrict__ gated,
                                                   float* __restrict__ partial1) {
    __shared__ float C_lds[64 * 256];     // exactly 64 KB
    const int t  = threadIdx.x;
    const int w  = t >> 6;                // wave 0..3
    const int L  = t & 63;
    const int rg = w & 1;                 // row group (32 rows)
    const int cg = w >> 1;                // col group (128 cols)
    const int lr = L & 31;
    const int lk = L >> 5;

    // ---- stationary B fragments: B[k][n] = W[n][256+k], bf16 ----
    // frag layout: lane holds B[k = s*16 + 8*lk + j][n = cg*128 + ct*32 + lr]
    short8 bfrag[4][4];
#pragma unroll
    for (int ct = 0; ct < 4; ct++) {
        const float* wr = &W[(size_t)(cg * 128 + ct * 32 + lr) * KIN + 256];
#pragma unroll
        for (int s = 0; s < 4; s++) {
            float4 x = *(const float4*)&wr[s * 16 + lk * 8];
            float4 y = *(const float4*)&wr[s * 16 + lk * 8 + 4];
            bfrag[ct][s] = pack8(x, y);
        }
    }

    const int c0 = (t & 63) * 4;          // epilogue: 4 owned columns
    float ssum[4] = {0.f, 0.f, 0.f, 0.f};
    float ssq[4]  = {0.f, 0.f, 0.f, 0.f};

    for (int tile = blockIdx.x; tile < NT2; tile += NBLK2) {
        // ---- A loads: lane L -> row tile*64+rg*32+lr, 8 contiguous f32/K-step
        const int row = tile * 64 + rg * 32 + lr;
        const float* ar = &nbr[(size_t)row * KD];
        float4 a0[4], a1[4];
#pragma unroll
        for (int s = 0; s < 4; s++) {
            a0[s] = *(const float4*)&ar[s * 16 + lk * 8];
            a1[s] = *(const float4*)&ar[s * 16 + lk * 8 + 4];
        }
        f32x16 acc[4];
#pragma unroll
        for (int ct = 0; ct < 4; ct++)
#pragma unroll
            for (int p = 0; p < 16; p++) acc[ct][p] = 0.f;

#pragma unroll
        for (int s = 0; s < 4; s++) {
            short8 af = pack8(a0[s], a1[s]);
#pragma unroll
            for (int ct = 0; ct < 4; ct++)
                acc[ct] = __builtin_amdgcn_mfma_f32_32x32x16_bf16(
                              af, bfrag[ct][s], acc[ct], 0, 0, 0);
        }

        __syncthreads();   // previous tile's epilogue reads complete
        // C/D layout: col = lane&31, row = (p&3) + 8*(p>>2) + 4*(lane>>5)
#pragma unroll
        for (int ct = 0; ct < 4; ct++) {
            const int col = cg * 128 + ct * 32 + lr;
#pragma unroll
            for (int p = 0; p < 16; p++) {
                int r = rg * 32 + (p & 3) + 8 * (p >> 2) + 4 * lk;
                C_lds[r * 256 + col] = acc[ct][p];
            }
        }
        __syncthreads();

        // ---- linear epilogue: wave w -> rows w, w+4, ..., w+60 ----
#pragma unroll 4
        for (int rr = 0; rr < 16; rr++) {
            const int lrow = rr * 4 + w;
            const int g    = tile * 64 + lrow;
            const u32 n    = (u32)g / 12u;
            const int iv   = nidx[g];
            const float mk = (iv != 0) ? 1.f : 0.f;
            float4 q = *(const float4*)&C_lds[lrow * 256 + c0];
            uint2 u1 = *(const uint2*)&P12[(size_t)n * 512 + c0];
            uint2 u2 = *(const uint2*)&P12[(size_t)iv * 512 + 256 + c0];
            float v0 = bflo(u1.x) + mk * (bflo(u2.x) + q.x);
            float v1 = bfhi(u1.x) + mk * (bfhi(u2.x) + q.y);
            float v2 = bflo(u1.y) + mk * (bflo(u2.y) + q.z);
            float v3 = bfhi(u1.y) + mk * (bfhi(u2.y) + q.w);
            *(uint2*)&gated[(size_t)g * 256 + c0] =
                make_uint2(pack2(v0, v1), pack2(v2, v3));
            ssum[0] += v0; ssq[0] += v0 * v0;
            ssum[1] += v1; ssq[1] += v1 * v1;
            ssum[2] += v2; ssq[2] += v2 * v2;
            ssum[3] += v3; ssq[3] += v3 * v3;
        }
    }

    // ---- block-level column reduction -> partial1[block][512] ----
    __syncthreads();
#pragma unroll
    for (int qq = 0; qq < 4; qq++) C_lds[w * 256 + c0 + qq] = ssum[qq];
    __syncthreads();
    {
        float s = C_lds[t] + C_lds[256 + t] + C_lds[512 + t] + C_lds[768 + t];
        partial1[(size_t)blockIdx.x * 512 + t] = s;
    }
    __syncthreads();
#pragma unroll
    for (int qq = 0; qq < 4; qq++) C_lds[w * 256 + c0 + qq] = ssq[qq];
    __syncthreads();
    {
        float s = C_lds[t] + C_lds[256 + t] + C_lds[512 + t] + C_lds[768 + t];
        partial1[(size_t)blockIdx.x * 512 + 256 + t] = s;
    }
}

// ---------------------------------------------------------------------------
// K2b: finalize BN1 -> bn1[c]=scale, bn1[256+c]=shift
// ---------------------------------------------------------------------------
__global__ __launch_bounds__(64) void k2b_bn1(const float* __restrict__ partial1,
                                              const float* __restrict__ gamma1,
                                              const float* __restrict__ beta1,
                                              float* __restrict__ bn1) {
    const int c = blockIdx.x;
    const int t = threadIdx.x;
    double s = 0.0, q = 0.0;
    for (int b = t; b < NBLK2; b += 64) {
        s += (double)partial1[(size_t)b * 512 + c];
        q += (double)partial1[(size_t)b * 512 + 256 + c];
    }
#pragma unroll
    for (int off = 32; off > 0; off >>= 1) {
        s += __shfl_down(s, off);
        q += __shfl_down(q, off);
    }
    if (t == 0) {
        double mean = s / (double)NMR;
        double var  = q / (double)NMR - mean * mean;
        float scale = gamma1[c] * rsqrtf((float)var + BN_EPS);
        bn1[c]       = scale;
        bn1[256 + c] = fmaf(-(float)mean, scale, beta1[c]);
    }
}

// ---------------------------------------------------------------------------
// K3: BN1 + sigmoid*softplus*mask, sum over M -> nsum; BN2 partials.
// Block = 16 atoms; thread (slot, c8): slot = atom, 8 filter + 8 core cols
// via uint4 (16 B) loads -> 256-B segments per 16-lane group.
// ---------------------------------------------------------------------------
__global__ __launch_bounds__(256) void k3_sum(const u16* __restrict__ gated,
                                              const int* __restrict__ nidx,
                                              const float* __restrict__ bn1,
                                              float* __restrict__ nsum,
                                              float* __restrict__ partial2) {
    __shared__ float red[16 * 128];
    const int t    = threadIdx.x;
    const int slot = t >> 4;
    const int c8   = (t & 15) * 8;
    const int n    = blockIdx.x * 16 + slot;

    float scf[8], shf[8], scc[8], shc[8];
#pragma unroll
    for (int j = 0; j < 8; j++) {
        scf[j] = bn1[c8 + j];       shf[j] = bn1[256 + c8 + j];
        scc[j] = bn1[128 + c8 + j]; shc[j] = bn1[384 + c8 + j];
    }
    float s8[8];
#pragma unroll
    for (int j = 0; j < 8; j++) s8[j] = 0.f;

    const size_t gb = (size_t)n * MN;
#pragma unroll 4
    for (int m = 0; m < MN; m++) {
        const size_t g = gb + m;
        const float mk = (nidx[g] != 0) ? 1.f : 0.f;
        uint4 uf = *(const uint4*)&gated[g * 256 + c8];
        uint4 uc = *(const uint4*)&gated[g * 256 + 128 + c8];
        float f[8], c[8];
        unp8(uf, f); unp8(uc, c);
#pragma unroll
        for (int j = 0; j < 8; j++) {
            float xf = fmaf(f[j], scf[j], shf[j]);
            float xc = fmaf(c[j], scc[j], shc[j]);
            s8[j] += sigmoidf_(xf) * softplusf(xc) * mk;
        }
    }
    *(float4*)&nsum[(size_t)n * 128 + c8]     = make_float4(s8[0], s8[1], s8[2], s8[3]);
    *(float4*)&nsum[(size_t)n * 128 + c8 + 4] = make_float4(s8[4], s8[5], s8[6], s8[7]);

#pragma unroll
    for (int j = 0; j < 8; j++) red[slot * 128 + c8 + j] = s8[j];
    __syncthreads();
    if (t < 128) {
        float s = 0.f;
#pragma unroll
        for (int q = 0; q < 16; q++) s += red[q * 128 + t];
        partial2[(size_t)blockIdx.x * 256 + t] = s;
    }
    __syncthreads();
#pragma unroll
    for (int j = 0; j < 8; j++) { float v = s8[j]; red[slot * 128 + c8 + j] = v * v; }
    __syncthreads();
    if (t < 128) {
        float s = 0.f;
#pragma unroll
        for (int q = 0; q < 16; q++) s += red[q * 128 + t];
        partial2[(size_t)blockIdx.x * 256 + 128 + t] = s;
    }
}

// ---------------------------------------------------------------------------
// K3b: finalize BN2 -> bn2[c]=scale, bn2[128+c]=shift
// ---------------------------------------------------------------------------
__global__ __launch_bounds__(64) void k3b_bn2(const float* __restrict__ partial2,
                                              const float* __restrict__ gamma2,
                                              const float* __restrict__ beta2,
                                              float* __restrict__ bn2) {
    const int c = blockIdx.x;
    const int t = threadIdx.x;
    double s = 0.0, q = 0.0;
    for (int b = t; b < NBLK3; b += 64) {
        s += (double)partial2[(size_t)b * 256 + c];
        q += (double)partial2[(size_t)b * 256 + 128 + c];
    }
#pragma unroll
    for (int off = 32; off > 0; off >>= 1) {
        s += __shfl_down(s, off);
        q += __shfl_down(q, off);
    }
    if (t == 0) {
        double mean = s / (double)NA;
        double var  = q / (double)NA - mean * mean;
        float scale = gamma2[c] * rsqrtf((float)var + BN_EPS);
        bn2[c]       = scale;
        bn2[128 + c] = fmaf(-(float)mean, scale, beta2[c]);
    }
}

// ---------------------------------------------------------------------------
// K4: out = softplus(atom_in + nbr_sumed*scale2 + shift2)
// ---------------------------------------------------------------------------
__global__ __launch_bounds__(256) void k4_out(const float* __restrict__ atom,
                                              const float* __restrict__ nsum,
                                              const float* __restrict__ bn2,
                                              float* __restrict__ out) {
    const int i  = blockIdx.x * 256 + threadIdx.x;   // float4 index, 1.6M exact
    const int c0 = (i & 31) * 4;
    float4 a = ((const float4*)atom)[i];
    float4 s = ((const float4*)nsum)[i];
    float4 r;
    r.x = softplusf(a.x + fmaf(s.x, bn2[c0 + 0], bn2[128 + c0 + 0]));
    r.y = softplusf(a.y + fmaf(s.y, bn2[c0 + 1], bn2[128 + c0 + 1]));
    r.z = softplusf(a.z + fmaf(s.z, bn2[c0 + 2], bn2[128 + c0 + 2]));
    r.w = softplusf(a.w + fmaf(s.w, bn2[c0 + 3], bn2[128 + c0 + 3]));
    ((float4*)out)[i] = r;
}

// ---------------------------------------------------------------------------
extern "C" void kernel_launch(void* const* d_in, const int* in_sizes, int n_in,
                              void* d_out, int out_size, void* d_ws, size_t ws_size,
                              hipStream_t stream) {
    const float* atom   = (const float*)d_in[0];
    const float* nbr    = (const float*)d_in[1];
    const int*   nidx   = (const int*)d_in[2];
    const float* W      = (const float*)d_in[3];
    // d_in[4] = b : unused — cancels exactly through BN1 mean subtraction
    const float* gamma1 = (const float*)d_in[5];
    const float* beta1  = (const float*)d_in[6];
    const float* gamma2 = (const float*)d_in[7];
    const float* beta2  = (const float*)d_in[8];
    float* out = (float*)d_out;

    // ws layout: P12 bf16 (51.2MB) | gated bf16 (307.2MB) | nsum | partials | bn
    u16* P12   = (u16*)d_ws;
    u16* gated = P12 + (size_t)NA * 512;
    float* nsum     = (float*)(gated + (size_t)NMR * 256);
    float* partial1 = nsum + (size_t)NA * 128;
    float* partial2 = partial1 + (size_t)NBLK2 * 512;
    float* bn1      = partial2 + (size_t)NBLK3 * 256;
    float* bn2      = bn1 + 512;

    k1_p12 <<<dim3(782, 2), 256, 0, stream>>>(atom, W, P12);
    k2_gated<<<NBLK2,       256, 0, stream>>>(nbr, nidx, W, P12, gated, partial1);
    k2b_bn1<<<256,           64, 0, stream>>>(partial1, gamma1, beta1, bn1);
    k3_sum <<<NBLK3,        256, 0, stream>>>(gated, nidx, bn1, nsum, partial2);
    k3b_bn2<<<128,           64, 0, stream>>>(partial2, gamma2, beta2, bn2);
    k4_out <<<6250,         256, 0, stream>>>(atom, nsum, bn2, out);
}

// Round 3
// 555.258 us; speedup vs baseline: 1.9572x; 1.3825x over previous
//
#include <hip/hip_runtime.h>

typedef unsigned int u32;
typedef unsigned short u16;
typedef __attribute__((ext_vector_type(8))) short short8;
typedef __attribute__((ext_vector_type(16))) float f32x16;

// Problem constants
#define NA   50000      // atoms
#define MN   12         // neighbors
#define FD   128        // atom feature len
#define KD   64         // nbr feature len
#define NMR  600000     // NA*MN edge rows
#define KIN  320        // 2F+K
#define NT2  9375       // NMR/64 tiles
#define NBLK2 512       // k2 persistent blocks
#define NBLK3 3125      // k3 blocks (16 atoms each)
#define BN_EPS 1e-5f
#define LOG2E 1.4426950408889634f
#define LN2   0.6931471805599453f

// ---- fast transcendentals: raw v_exp_f32 / v_log_f32 / v_rcp_f32 ----
#if __has_builtin(__builtin_amdgcn_exp2f)
#define EXP2F(x) __builtin_amdgcn_exp2f(x)
#else
#define EXP2F(x) exp2f(x)
#endif
#if __has_builtin(__builtin_amdgcn_logf)
#define LOG2F(x) __builtin_amdgcn_logf(x)
#else
#define LOG2F(x) log2f(x)
#endif
#if __has_builtin(__builtin_amdgcn_rcpf)
#define RCPF(x) __builtin_amdgcn_rcpf(x)
#else
#define RCPF(x) (1.f / (x))
#endif

__device__ __forceinline__ float fast_sigmoid(float x) {
    return RCPF(1.f + EXP2F(-x * LOG2E));    // 1/(1+e^-x)
}
__device__ __forceinline__ float fast_softplus(float x) {
    float e = EXP2F(-fabsf(x) * LOG2E);      // e^{-|x|}
    return fmaxf(x, 0.f) + LN2 * LOG2F(1.f + e);
}

// ---- manual bf16 (RNE) helpers ----
__device__ __forceinline__ u32 f2bf_bits(float f) {
    u32 u = __float_as_uint(f);
    return u + 0x7fffu + ((u >> 16) & 1u);
}
__device__ __forceinline__ u32 pack2(float lo, float hi) {
    return (f2bf_bits(lo) >> 16) | (f2bf_bits(hi) & 0xffff0000u);
}
__device__ __forceinline__ float bflo(u32 u) { return __uint_as_float(u << 16); }
__device__ __forceinline__ float bfhi(u32 u) { return __uint_as_float(u & 0xffff0000u); }
__device__ __forceinline__ short8 pack8(float4 x, float4 y) {
    union { short8 s; uint4 u; } cv;
    cv.u = make_uint4(pack2(x.x, x.y), pack2(x.z, x.w),
                      pack2(y.x, y.y), pack2(y.z, y.w));
    return cv.s;
}
__device__ __forceinline__ void unp8(uint4 u, float* f) {
    f[0] = bflo(u.x); f[1] = bfhi(u.x); f[2] = bflo(u.y); f[3] = bfhi(u.y);
    f[4] = bflo(u.z); f[5] = bfhi(u.z); f[6] = bflo(u.w); f[7] = bfhi(u.w);
}

// ---------------------------------------------------------------------------
// K1 (MFMA): P12[n][0:256] = atom@W1^T, [256:512] = atom@W2^T, bf16 out.
// Bias skipped (cancels through BN1 mean). Stationary B in VGPRs, K=128
// fully unrolled, zero LDS. Block = 4 waves = 64 rows x 256 cols (one yb half).
// wave w: rows 32*(w&1), cols 128*(w>>1).
// ---------------------------------------------------------------------------
__global__ __launch_bounds__(256) void k1_p12(const float* __restrict__ atom,
                                              const float* __restrict__ W,
                                              u16* __restrict__ P12) {
    const int t  = threadIdx.x;
    const int w  = t >> 6;
    const int L  = t & 63;
    const int rg = w & 1, cg = w >> 1;
    const int lr = L & 31, lk = L >> 5;
    const int yb  = blockIdx.y;
    const int kwb = yb * 128;
    const int r0  = blockIdx.x * 64 + rg * 32;

    // B frags: lane holds B[k = s*16 + 8*lk + j][n = cg*128 + ct*32 + lr]
    short8 bfrag[4][8];
#pragma unroll
    for (int ct = 0; ct < 4; ct++) {
        const float* wr = &W[(size_t)(cg * 128 + ct * 32 + lr) * KIN + kwb];
#pragma unroll
        for (int s = 0; s < 8; s++) {
            float4 x = *(const float4*)&wr[s * 16 + lk * 8];
            float4 y = *(const float4*)&wr[s * 16 + lk * 8 + 4];
            bfrag[ct][s] = pack8(x, y);
        }
    }
    // A frags: lane holds A[m = lr][k = s*16 + 8*lk + j]
    int row = r0 + lr; if (row > NA - 1) row = NA - 1;
    const float* ar = &atom[(size_t)row * FD];
    short8 afrag[8];
#pragma unroll
    for (int s = 0; s < 8; s++) {
        float4 x = *(const float4*)&ar[s * 16 + lk * 8];
        float4 y = *(const float4*)&ar[s * 16 + lk * 8 + 4];
        afrag[s] = pack8(x, y);
    }
    f32x16 acc[4];
#pragma unroll
    for (int ct = 0; ct < 4; ct++)
#pragma unroll
        for (int p = 0; p < 16; p++) acc[ct][p] = 0.f;
#pragma unroll
    for (int s = 0; s < 8; s++)
#pragma unroll
        for (int ct = 0; ct < 4; ct++)
            acc[ct] = __builtin_amdgcn_mfma_f32_32x32x16_bf16(
                          afrag[s], bfrag[ct][s], acc[ct], 0, 0, 0);
    // store directly from MFMA C layout: col=lane&31, row=(p&3)+8*(p>>2)+4*lk
#pragma unroll
    for (int ct = 0; ct < 4; ct++) {
        const int c = cg * 128 + ct * 32 + lr;
#pragma unroll
        for (int p = 0; p < 16; p++) {
            int r = r0 + (p & 3) + 8 * (p >> 2) + 4 * lk;
            if (r < NA)
                P12[(size_t)r * 512 + yb * 256 + c] =
                    (u16)(f2bf_bits(acc[ct][p]) >> 16);
        }
    }
}

// ---------------------------------------------------------------------------
// K2 (MFMA): Q = nbr @ W3^T, B stationary in VGPRs; C staged through LDS to
// linear layout; epilogue fuses P1 + mask*(P2 + Q), bf16 store, BN1 partials.
// Software-pipelined: next tile's A rows prefetched over the epilogue.
// ---------------------------------------------------------------------------
__global__ __launch_bounds__(256, 2) void k2_gated(const float* __restrict__ nbr,
                                                   const int* __restrict__ nidx,
                                                   const float* __restrict__ W,
                                                   const u16* __restrict__ P12,
                                                   u16* __restrict__ gated,
                                                   float* __restrict__ partial1) {
    __shared__ float C_lds[64 * 256];     // 64 KB
    const int t  = threadIdx.x;
    const int w  = t >> 6;
    const int L  = t & 63;
    const int rg = w & 1;
    const int cg = w >> 1;
    const int lr = L & 31;
    const int lk = L >> 5;

    // stationary B frags: B[k][n] = W[n][256+k]
    short8 bfrag[4][4];
#pragma unroll
    for (int ct = 0; ct < 4; ct++) {
        const float* wr = &W[(size_t)(cg * 128 + ct * 32 + lr) * KIN + 256];
#pragma unroll
        for (int s = 0; s < 4; s++) {
            float4 x = *(const float4*)&wr[s * 16 + lk * 8];
            float4 y = *(const float4*)&wr[s * 16 + lk * 8 + 4];
            bfrag[ct][s] = pack8(x, y);
        }
    }

    const int c0 = (t & 63) * 4;
    float ssum[4] = {0.f, 0.f, 0.f, 0.f};
    float ssq[4]  = {0.f, 0.f, 0.f, 0.f};

    int tile = blockIdx.x;
    float4 a0[4], a1[4];
    {
        const float* ar = &nbr[(size_t)(tile * 64 + rg * 32 + lr) * KD];
#pragma unroll
        for (int s = 0; s < 4; s++) {
            a0[s] = *(const float4*)&ar[s * 16 + lk * 8];
            a1[s] = *(const float4*)&ar[s * 16 + lk * 8 + 4];
        }
    }

    for (; tile < NT2; tile += NBLK2) {
        short8 af[4];
#pragma unroll
        for (int s = 0; s < 4; s++) af[s] = pack8(a0[s], a1[s]);

        // prefetch next tile's A rows (flies over C-stage + epilogue)
        const int next = tile + NBLK2;
        if (next < NT2) {
            const float* ar = &nbr[(size_t)(next * 64 + rg * 32 + lr) * KD];
#pragma unroll
            for (int s = 0; s < 4; s++) {
                a0[s] = *(const float4*)&ar[s * 16 + lk * 8];
                a1[s] = *(const float4*)&ar[s * 16 + lk * 8 + 4];
            }
        }

        f32x16 acc[4];
#pragma unroll
        for (int ct = 0; ct < 4; ct++)
#pragma unroll
            for (int p = 0; p < 16; p++) acc[ct][p] = 0.f;
#pragma unroll
        for (int s = 0; s < 4; s++)
#pragma unroll
            for (int ct = 0; ct < 4; ct++)
                acc[ct] = __builtin_amdgcn_mfma_f32_32x32x16_bf16(
                              af[s], bfrag[ct][s], acc[ct], 0, 0, 0);

        __syncthreads();   // previous tile's epilogue reads complete
#pragma unroll
        for (int ct = 0; ct < 4; ct++) {
            const int col = cg * 128 + ct * 32 + lr;
#pragma unroll
            for (int p = 0; p < 16; p++) {
                int r = rg * 32 + (p & 3) + 8 * (p >> 2) + 4 * lk;
                C_lds[r * 256 + col] = acc[ct][p];
            }
        }
        __syncthreads();

        // linear epilogue: wave w -> rows w, w+4, ..., w+60
#pragma unroll 8
        for (int rr = 0; rr < 16; rr++) {
            const int lrow = rr * 4 + w;
            const int g    = tile * 64 + lrow;
            const u32 n    = (u32)g / 12u;
            const int iv   = nidx[g];
            const float mk = (iv != 0) ? 1.f : 0.f;
            float4 q = *(const float4*)&C_lds[lrow * 256 + c0];
            uint2 u1 = *(const uint2*)&P12[(size_t)n * 512 + c0];
            uint2 u2 = *(const uint2*)&P12[(size_t)iv * 512 + 256 + c0];
            float v0 = bflo(u1.x) + mk * (bflo(u2.x) + q.x);
            float v1 = bfhi(u1.x) + mk * (bfhi(u2.x) + q.y);
            float v2 = bflo(u1.y) + mk * (bflo(u2.y) + q.z);
            float v3 = bfhi(u1.y) + mk * (bfhi(u2.y) + q.w);
            *(uint2*)&gated[(size_t)g * 256 + c0] =
                make_uint2(pack2(v0, v1), pack2(v2, v3));
            ssum[0] += v0; ssq[0] += v0 * v0;
            ssum[1] += v1; ssq[1] += v1 * v1;
            ssum[2] += v2; ssq[2] += v2 * v2;
            ssum[3] += v3; ssq[3] += v3 * v3;
        }
    }

    // block-level column reduction -> partial1[block][512]
    __syncthreads();
#pragma unroll
    for (int qq = 0; qq < 4; qq++) C_lds[w * 256 + c0 + qq] = ssum[qq];
    __syncthreads();
    {
        float s = C_lds[t] + C_lds[256 + t] + C_lds[512 + t] + C_lds[768 + t];
        partial1[(size_t)blockIdx.x * 512 + t] = s;
    }
    __syncthreads();
#pragma unroll
    for (int qq = 0; qq < 4; qq++) C_lds[w * 256 + c0 + qq] = ssq[qq];
    __syncthreads();
    {
        float s = C_lds[t] + C_lds[256 + t] + C_lds[512 + t] + C_lds[768 + t];
        partial1[(size_t)blockIdx.x * 512 + 256 + t] = s;
    }
}

// ---------------------------------------------------------------------------
// K2b: finalize BN1 -> bn1[c]=scale, bn1[256+c]=shift
// ---------------------------------------------------------------------------
__global__ __launch_bounds__(64) void k2b_bn1(const float* __restrict__ partial1,
                                              const float* __restrict__ gamma1,
                                              const float* __restrict__ beta1,
                                              float* __restrict__ bn1) {
    const int c = blockIdx.x;
    const int t = threadIdx.x;
    double s = 0.0, q = 0.0;
    for (int b = t; b < NBLK2; b += 64) {
        s += (double)partial1[(size_t)b * 512 + c];
        q += (double)partial1[(size_t)b * 512 + 256 + c];
    }
#pragma unroll
    for (int off = 32; off > 0; off >>= 1) {
        s += __shfl_down(s, off);
        q += __shfl_down(q, off);
    }
    if (t == 0) {
        double mean = s / (double)NMR;
        double var  = q / (double)NMR - mean * mean;
        float scale = gamma1[c] * rsqrtf((float)var + BN_EPS);
        bn1[c]       = scale;
        bn1[256 + c] = fmaf(-(float)mean, scale, beta1[c]);
    }
}

// ---------------------------------------------------------------------------
// K3: BN1 + sigmoid*softplus*mask, sum over M -> nsum; BN2 partials.
// Raw v_exp/v_log/v_rcp transcendentals (~24 slots/pair vs ~295 for libm).
// ---------------------------------------------------------------------------
__global__ __launch_bounds__(256) void k3_sum(const u16* __restrict__ gated,
                                              const int* __restrict__ nidx,
                                              const float* __restrict__ bn1,
                                              float* __restrict__ nsum,
                                              float* __restrict__ partial2) {
    __shared__ float red[16 * 128];
    const int t    = threadIdx.x;
    const int slot = t >> 4;
    const int c8   = (t & 15) * 8;
    const int n    = blockIdx.x * 16 + slot;

    float scf[8], shf[8], scc[8], shc[8];
#pragma unroll
    for (int j = 0; j < 8; j++) {
        scf[j] = bn1[c8 + j];       shf[j] = bn1[256 + c8 + j];
        scc[j] = bn1[128 + c8 + j]; shc[j] = bn1[384 + c8 + j];
    }
    float s8[8];
#pragma unroll
    for (int j = 0; j < 8; j++) s8[j] = 0.f;

    const size_t gb = (size_t)n * MN;
#pragma unroll 4
    for (int m = 0; m < MN; m++) {
        const size_t g = gb + m;
        const float mk = (nidx[g] != 0) ? 1.f : 0.f;
        uint4 uf = *(const uint4*)&gated[g * 256 + c8];
        uint4 uc = *(const uint4*)&gated[g * 256 + 128 + c8];
        float f[8], c[8];
        unp8(uf, f); unp8(uc, c);
#pragma unroll
        for (int j = 0; j < 8; j++) {
            float xf = fmaf(f[j], scf[j], shf[j]);
            float xc = fmaf(c[j], scc[j], shc[j]);
            s8[j] += fast_sigmoid(xf) * fast_softplus(xc) * mk;
        }
    }
    *(float4*)&nsum[(size_t)n * 128 + c8]     = make_float4(s8[0], s8[1], s8[2], s8[3]);
    *(float4*)&nsum[(size_t)n * 128 + c8 + 4] = make_float4(s8[4], s8[5], s8[6], s8[7]);

#pragma unroll
    for (int j = 0; j < 8; j++) red[slot * 128 + c8 + j] = s8[j];
    __syncthreads();
    if (t < 128) {
        float s = 0.f;
#pragma unroll
        for (int q = 0; q < 16; q++) s += red[q * 128 + t];
        partial2[(size_t)blockIdx.x * 256 + t] = s;
    }
    __syncthreads();
#pragma unroll
    for (int j = 0; j < 8; j++) { float v = s8[j]; red[slot * 128 + c8 + j] = v * v; }
    __syncthreads();
    if (t < 128) {
        float s = 0.f;
#pragma unroll
        for (int q = 0; q < 16; q++) s += red[q * 128 + t];
        partial2[(size_t)blockIdx.x * 256 + 128 + t] = s;
    }
}

// ---------------------------------------------------------------------------
// K3b: finalize BN2 -> bn2[c]=scale, bn2[128+c]=shift
// ---------------------------------------------------------------------------
__global__ __launch_bounds__(64) void k3b_bn2(const float* __restrict__ partial2,
                                              const float* __restrict__ gamma2,
                                              const float* __restrict__ beta2,
                                              float* __restrict__ bn2) {
    const int c = blockIdx.x;
    const int t = threadIdx.x;
    double s = 0.0, q = 0.0;
    for (int b = t; b < NBLK3; b += 64) {
        s += (double)partial2[(size_t)b * 256 + c];
        q += (double)partial2[(size_t)b * 256 + 128 + c];
    }
#pragma unroll
    for (int off = 32; off > 0; off >>= 1) {
        s += __shfl_down(s, off);
        q += __shfl_down(q, off);
    }
    if (t == 0) {
        double mean = s / (double)NA;
        double var  = q / (double)NA - mean * mean;
        float scale = gamma2[c] * rsqrtf((float)var + BN_EPS);
        bn2[c]       = scale;
        bn2[128 + c] = fmaf(-(float)mean, scale, beta2[c]);
    }
}

// ---------------------------------------------------------------------------
// K4: out = softplus(atom_in + nbr_sumed*scale2 + shift2)
// ---------------------------------------------------------------------------
__global__ __launch_bounds__(256) void k4_out(const float* __restrict__ atom,
                                              const float* __restrict__ nsum,
                                              const float* __restrict__ bn2,
                                              float* __restrict__ out) {
    const int i  = blockIdx.x * 256 + threadIdx.x;   // float4 index, 1.6M exact
    const int c0 = (i & 31) * 4;
    float4 a = ((const float4*)atom)[i];
    float4 s = ((const float4*)nsum)[i];
    float4 r;
    r.x = fast_softplus(a.x + fmaf(s.x, bn2[c0 + 0], bn2[128 + c0 + 0]));
    r.y = fast_softplus(a.y + fmaf(s.y, bn2[c0 + 1], bn2[128 + c0 + 1]));
    r.z = fast_softplus(a.z + fmaf(s.z, bn2[c0 + 2], bn2[128 + c0 + 2]));
    r.w = fast_softplus(a.w + fmaf(s.w, bn2[c0 + 3], bn2[128 + c0 + 3]));
    ((float4*)out)[i] = r;
}

// ---------------------------------------------------------------------------
extern "C" void kernel_launch(void* const* d_in, const int* in_sizes, int n_in,
                              void* d_out, int out_size, void* d_ws, size_t ws_size,
                              hipStream_t stream) {
    const float* atom   = (const float*)d_in[0];
    const float* nbr    = (const float*)d_in[1];
    const int*   nidx   = (const int*)d_in[2];
    const float* W      = (const float*)d_in[3];
    // d_in[4] = b : unused — cancels exactly through BN1 mean subtraction
    const float* gamma1 = (const float*)d_in[5];
    const float* beta1  = (const float*)d_in[6];
    const float* gamma2 = (const float*)d_in[7];
    const float* beta2  = (const float*)d_in[8];
    float* out = (float*)d_out;

    // ws layout: P12 bf16 (51.2MB) | gated bf16 (307.2MB) | nsum | partials | bn
    u16* P12   = (u16*)d_ws;
    u16* gated = P12 + (size_t)NA * 512;
    float* nsum     = (float*)(gated + (size_t)NMR * 256);
    float* partial1 = nsum + (size_t)NA * 128;
    float* partial2 = partial1 + (size_t)NBLK2 * 512;
    float* bn1      = partial2 + (size_t)NBLK3 * 256;
    float* bn2      = bn1 + 512;

    k1_p12 <<<dim3(782, 2), 256, 0, stream>>>(atom, W, P12);
    k2_gated<<<NBLK2,       256, 0, stream>>>(nbr, nidx, W, P12, gated, partial1);
    k2b_bn1<<<256,           64, 0, stream>>>(partial1, gamma1, beta1, bn1);
    k3_sum <<<NBLK3,        256, 0, stream>>>(gated, nidx, bn1, nsum, partial2);
    k3b_bn2<<<128,           64, 0, stream>>>(partial2, gamma2, beta2, bn2);
    k4_out <<<6250,         256, 0, stream>>>(atom, nsum, bn2, out);
}